// Round 8
// baseline (269.385 us; speedup 1.0000x reference)
//
#include <hip/hip_runtime.h>
#include <hip/hip_bf16.h>

// AttnBlock: GroupNorm + single-head attention (N=1024 tokens, C=512) + residual.
// B=16. fp16 single-plane MFMA GEMMs (passing since R6, absmax 0.03125).
// R8 changes vs R7 (252.7 us):
//  - R7's 2-phase pipeline still drained vmcnt(0) at the per-step barrier
//    (T4 lesson: pipeline-with-drain0 == no pipeline). Can't remove the drain
//    in plain HIP -> hide it with TLP instead: BK 64->32, dbuf 2x16KB = 32KB
//    LDS (was 64KB) -> ~5 blocks/CU co-resident; other blocks cover each
//    block's barrier drain.
//  - New LDS layout (64B logical rows would be 8-way bank-conflicted):
//    row-pairs packed into 128B groups; byte = (row>>1)*128 + S*16,
//    S = (c | (row&1)<<2) ^ ((row>>1)&7). Frag reads: each 4-bank group hit
//    exactly 2x per wave = free. Staging source per lane uses the SAME
//    sel=(lane&7)^(lane>>3) involution: srcrow = 2*(lane>>3)+(sel>>2),
//    srccol = (sel&3)*8; +16 rows per 1KB chunk. Verified algebraically
//    (write dest->(row,c) == read (row,c)->byte).
//  - Numerics bit-identical to R7: absmax must remain exactly 0.03125.

#define B_ 16
#define C_ 512
#define NTOK_ 1024
#define CPG_ 16
#define EPS_ 1e-5f
#define QSCALE_ 0.04419417382415922f  // 512^-0.5

typedef __attribute__((ext_vector_type(8))) _Float16 f16x8;  // 4 VGPR
typedef __attribute__((ext_vector_type(4))) float f32x4;
typedef const void __attribute__((address_space(1)))* gas1_t;
typedef void __attribute__((address_space(3)))* las3_t;

__device__ __forceinline__ ushort f2h(float x) {
    union { _Float16 h; ushort u; } c; c.h = (_Float16)x; return c.u;
}

// =================== fp16 MFMA GEMM core (BK=32, 2x16KB dbuf) ===================
// C[128 x 128] += A · B^T (rows of B = output cols), fp16 (as ushort*), K%32==0.
// acc[m][n]: wave (wm,wn); C row = wm*64+m*16+4*lk+reg, col = wn*64+n*16+lrow.
// LDS buffer 16KB: A region [0,8K), B [8K,16K). Layout per region: logical
// (row 0..127, chunk c 0..3 of 16B) at byte (row>>1)*128 + S*16,
// S = (c | (row&1)<<2) ^ ((row>>1)&7).
__device__ __forceinline__ void gemm_core_f16(
    const ushort* __restrict__ A, int lda,
    const ushort* __restrict__ B, int ldb,
    int K, f32x4 acc[4][4])
{
    __shared__ alignas(16) char ldsc[2][16384];
    const int tid  = threadIdx.x;
    const int wave = tid >> 6, lane = tid & 63;
    const int wm = wave >> 1, wn = wave & 1;
    const int lrow = lane & 15, lk = lane >> 4;

    // staging roles: waves 0,1 -> A rows [0,64)/[64,128); waves 2,3 -> B same.
    const int isB = wave >> 1;
    const ushort* P = isB ? B : A;
    const int ld = isB ? ldb : lda;
    const int sel = (lane & 7) ^ (lane >> 3);
    const int row0 = ((wave & 1) << 6) + ((lane >> 3) << 1) + (sel >> 2);
    const ushort* src0 = P + (size_t)row0 * ld + (sel & 3) * 8;
    const int dstoff = (isB << 13) + ((wave & 1) << 12);  // 4KB per wave

    const int nsteps = K >> 5;

    // prologue: stage tile 0 into buffer 0 (4 x 1KB per wave; +16 rows per j)
#pragma unroll
    for (int j = 0; j < 4; ++j) {
        __builtin_amdgcn_global_load_lds(
            (gas1_t)(src0 + (size_t)(j << 4) * ld),
            (las3_t)(&ldsc[0][0] + dstoff + (j << 10)), 16, 0, 0);
    }
    __syncthreads();  // tile 0 resident

    for (int t = 0; t < nsteps; ++t) {
        const char* cur = &ldsc[t & 1][0];
        // issue next tile's stage first: latency hides under ds_read+MFMA
        if (t + 1 < nsteps) {
            const ushort* st = src0 + (t + 1) * 32;
            char* nxt = &ldsc[(t + 1) & 1][0] + dstoff;
#pragma unroll
            for (int j = 0; j < 4; ++j) {
                __builtin_amdgcn_global_load_lds(
                    (gas1_t)(st + (size_t)(j << 4) * ld),
                    (las3_t)(nxt + (j << 10)), 16, 0, 0);
            }
        }

        f16x8 af[4], bf[4];
#pragma unroll
        for (int m = 0; m < 4; ++m) {
            int row = wm * 64 + m * 16 + lrow;
            int a = row >> 1;
            int S = (lk | ((row & 1) << 2)) ^ (a & 7);
            af[m] = *(const f16x8*)(cur + (a << 7) + (S << 4));
        }
#pragma unroll
        for (int n = 0; n < 4; ++n) {
            int row = wn * 64 + n * 16 + lrow;
            int a = row >> 1;
            int S = (lk | ((row & 1) << 2)) ^ (a & 7);
            bf[n] = *(const f16x8*)(cur + 8192 + (a << 7) + (S << 4));
        }
#pragma unroll
        for (int m = 0; m < 4; ++m)
#pragma unroll
            for (int n = 0; n < 4; ++n)
                acc[m][n] = __builtin_amdgcn_mfma_f32_16x16x32_f16(af[m], bf[n], acc[m][n], 0, 0, 0);
        // one barrier/K-step: drains stage(t+1) + all waves' reads of cur
        __syncthreads();
    }
}

#define ACC_ZERO(acc) do { \
    _Pragma("unroll") for (int m_ = 0; m_ < 4; ++m_) \
    _Pragma("unroll") for (int n_ = 0; n_ < 4; ++n_) \
        acc[m_][n_] = (f32x4){0.f, 0.f, 0.f, 0.f}; \
} while (0)

// ---------------- 1. GroupNorm + affine + transpose -> h fp16 [b][n][c] ----------------
__global__ __launch_bounds__(256) void gn_prep_kernel(
    const float* __restrict__ x, const float* __restrict__ gw,
    const float* __restrict__ gb, ushort* __restrict__ h16) {
    __shared__ float sx[16][1028];   // +4 pad
    __shared__ float red[8];
    __shared__ float smu, srstd;
    __shared__ float s_sc[16], s_bi[16];
    int bg = blockIdx.x;
    int b = bg >> 5, g = bg & 31;
    const float* xp = x + ((size_t)(b * C_ + g * CPG_) << 10);
    int tid = threadIdx.x;
    float s = 0.f, ss = 0.f;
    for (int i = tid; i < 4096; i += 256) {   // 16 ch * 256 f32x4
        int c = i >> 8, n4 = (i & 255) << 2;
        f32x4 v = *(const f32x4*)&xp[((size_t)c << 10) + n4];
        *(f32x4*)&sx[c][n4] = v;
        s += v[0] + v[1] + v[2] + v[3];
        ss += v[0]*v[0] + v[1]*v[1] + v[2]*v[2] + v[3]*v[3];
    }
#pragma unroll
    for (int off = 32; off; off >>= 1) {
        s += __shfl_down(s, off);
        ss += __shfl_down(ss, off);
    }
    int wid = tid >> 6, lane = tid & 63;
    if (lane == 0) { red[wid] = s; red[wid + 4] = ss; }
    __syncthreads();
    if (tid == 0) {
        float S = red[0] + red[1] + red[2] + red[3];
        float SS = red[4] + red[5] + red[6] + red[7];
        float mu = S * (1.f / 16384.f);
        float var = SS * (1.f / 16384.f) - mu * mu;
        smu = mu;
        srstd = rsqrtf(var + EPS_);
    }
    __syncthreads();
    if (tid < CPG_) {
        int c = g * CPG_ + tid;
        float sc = srstd * gw[c];
        s_sc[tid] = sc;
        s_bi[tid] = gb[c] - smu * sc;
    }
    __syncthreads();
#pragma unroll
    for (int jn = 0; jn < 4; ++jn) {
        int n = (tid << 2) + jn;
        union { ushort u[16]; uint4 v[2]; } pk;
#pragma unroll
        for (int c = 0; c < 16; ++c)
            pk.u[c] = f2h(sx[c][n] * s_sc[c] + s_bi[c]);
        size_t ob = (((size_t)b << 10) + n) * C_ + g * CPG_;
        *(uint4*)&h16[ob] = pk.v[0];
        *(uint4*)&h16[ob + 8] = pk.v[1];
    }
}

// ---------------- 3. prep_w: wq, wk -> fp16 ----------------
__global__ __launch_bounds__(256) void prep_w_kernel(
    const float* __restrict__ wq, const float* __restrict__ wk,
    ushort* __restrict__ wq16, ushort* __restrict__ wk16) {
    int i = blockIdx.x * 256 + threadIdx.x;
    union { ushort u[4]; ushort4 v; } h;
    f32x4 a = ((const f32x4*)wq)[i];
#pragma unroll
    for (int j = 0; j < 4; ++j) h.u[j] = f2h(a[j]);
    ((ushort4*)wq16)[i] = h.v;
    f32x4 b = ((const f32x4*)wk)[i];
#pragma unroll
    for (int j = 0; j < 4; ++j) h.u[j] = f2h(b[j]);
    ((ushort4*)wk16)[i] = h.v;
}

// ---------------- 4. Weff = wp @ wv (fp32 VALU) -> fp16 ----------------
__global__ __launch_bounds__(256) void weff_kernel(
    const float* __restrict__ wp, const float* __restrict__ wv,
    ushort* __restrict__ we16) {
    __shared__ float As[16][68], Bs[16][68];
    int tid = threadIdx.x, ty = tid >> 4, tx = tid & 15;
    int c0 = blockIdx.x << 6, p0 = blockIdx.y << 6;
    int a_row = tid >> 2, a_kq = tid & 3;
    int b_m = tid >> 4, b_cq = tid & 15;
    float acc[4][4] = {};
    for (int k0 = 0; k0 < C_; k0 += 16) {
        f32x4 a4 = *(const f32x4*)&wp[(size_t)(p0 + a_row) * C_ + k0 + a_kq * 4];
        As[a_kq * 4 + 0][a_row] = a4[0]; As[a_kq * 4 + 1][a_row] = a4[1];
        As[a_kq * 4 + 2][a_row] = a4[2]; As[a_kq * 4 + 3][a_row] = a4[3];
        *(f32x4*)&Bs[b_m][b_cq * 4] =
            *(const f32x4*)&wv[(size_t)(k0 + b_m) * C_ + c0 + b_cq * 4];
        __syncthreads();
#pragma unroll
        for (int kk = 0; kk < 16; ++kk) {
            f32x4 av = *(const f32x4*)&As[kk][ty << 2];
            f32x4 bv = *(const f32x4*)&Bs[kk][tx << 2];
#pragma unroll
            for (int i = 0; i < 4; ++i)
#pragma unroll
                for (int j = 0; j < 4; ++j) acc[i][j] += av[i] * bv[j];
        }
        __syncthreads();
    }
#pragma unroll
    for (int i = 0; i < 4; ++i) {
        union { ushort u[4]; ushort4 v; } hh;
#pragma unroll
        for (int j = 0; j < 4; ++j) hh.u[j] = f2h(acc[i][j]);
        *(ushort4*)&we16[(size_t)(p0 + ty * 4 + i) * C_ + c0 + tx * 4] = hh.v;
    }
}

// ---------------- 5. bsum[p] = bp[p] + sum_o wp[p][o]*bv[o] ----------------
__global__ __launch_bounds__(256) void bsum_kernel(
    const float* __restrict__ wp, const float* __restrict__ bv,
    const float* __restrict__ bp, float* __restrict__ bsum) {
    int p = blockIdx.x * 4 + (threadIdx.x >> 6);   // grid 128 -> p in [0,512)
    int lane = threadIdx.x & 63;
    const float* row = wp + (size_t)p * C_;
    f32x4 w0 = *(const f32x4*)&row[lane * 8];
    f32x4 w1 = *(const f32x4*)&row[lane * 8 + 4];
    f32x4 b0 = *(const f32x4*)&bv[lane * 8];
    f32x4 b1 = *(const f32x4*)&bv[lane * 8 + 4];
    float s = w0[0]*b0[0] + w0[1]*b0[1] + w0[2]*b0[2] + w0[3]*b0[3]
            + w1[0]*b1[0] + w1[1]*b1[1] + w1[2]*b1[2] + w1[3]*b1[3];
#pragma unroll
    for (int off = 32; off; off >>= 1) s += __shfl_down(s, off);
    if (lane == 0) bsum[p] = bp[p] + s;
}

// ---------------- 6. qkv GEMM (q, k, vp^T from h) ----------------
__global__ __launch_bounds__(256) void gemm_qkv(
    const ushort* __restrict__ h16,
    const ushort* __restrict__ wq16, const ushort* __restrict__ wk16,
    const ushort* __restrict__ we16,
    const float* __restrict__ bq, const float* __restrict__ bk,
    ushort* __restrict__ q16, ushort* __restrict__ k16,
    ushort* __restrict__ vpt16) {
    // XCD-chunked bijective swizzle (nwg=1536, %8==0)
    int D = blockIdx.x + 12 * blockIdx.y;
    int L = ((D & 7) * 192) + (D >> 3);
    int lx = L % 12, mt = L / 12;
    int wsel = lx >> 2, ct = lx & 3;

    const ushort* Bw = wsel == 0 ? wq16 : (wsel == 1 ? wk16 : we16);
    const float* bias = wsel == 0 ? bq : bk;

    f32x4 acc[4][4]; ACC_ZERO(acc);
    gemm_core_f16(h16 + (size_t)mt * 128 * C_, C_,
                  Bw + (size_t)ct * 128 * C_, C_, C_, acc);

    int tid = threadIdx.x, wave = tid >> 6, lane = tid & 63;
    int wm = wave >> 1, wn = wave & 1, lrow = lane & 15, lk = lane >> 4;

    if (wsel < 2) {
        ushort* oh = wsel ? k16 : q16;
        float scale = wsel ? 1.f : QSCALE_;
#pragma unroll
        for (int mf = 0; mf < 4; ++mf) {
            int gm = mt * 128 + wm * 64 + mf * 16 + 4 * lk;
#pragma unroll
            for (int nf = 0; nf < 4; ++nf) {
                int gc = ct * 128 + wn * 64 + nf * 16 + lrow;
                float bi = bias[gc];
#pragma unroll
                for (int rg = 0; rg < 4; ++rg)
                    oh[(size_t)(gm + rg) * C_ + gc] = f2h((acc[mf][nf][rg] + bi) * scale);
            }
        }
    } else {
        // vp^T [b][p][n]: 4 consecutive token-rows per reg-quad -> 8B stores
#pragma unroll
        for (int mf = 0; mf < 4; ++mf) {
            int gm0 = mt * 128 + wm * 64 + mf * 16 + 4 * lk;
            int b = gm0 >> 10, nl = gm0 & 1023;
#pragma unroll
            for (int nf = 0; nf < 4; ++nf) {
                int p = ct * 128 + wn * 64 + nf * 16 + lrow;
                union { ushort u[4]; ushort4 v; } hv;
#pragma unroll
                for (int rg = 0; rg < 4; ++rg) hv.u[rg] = f2h(acc[mf][nf][rg]);
                *(ushort4*)&vpt16[((size_t)b * C_ + p) * NTOK_ + nl] = hv.v;
            }
        }
    }
}

// ---------------- 7. scores = q @ k^T (per batch), fp32 out ----------------
__global__ __launch_bounds__(256) void gemm_scores(
    const ushort* __restrict__ q16, const ushort* __restrict__ k16,
    float* __restrict__ s) {
    // swizzle (nwg=1024)
    int D = blockIdx.x + (blockIdx.y << 3) + (blockIdx.z << 6);
    int L = ((D & 7) << 7) + (D >> 3);
    int nx = L & 7, my = (L >> 3) & 7, b = L >> 6;

    size_t ao = ((size_t)b * NTOK_ + my * 128) * C_;
    size_t bo = ((size_t)b * NTOK_ + nx * 128) * C_;
    f32x4 acc[4][4]; ACC_ZERO(acc);
    gemm_core_f16(q16 + ao, C_, k16 + bo, C_, C_, acc);

    int tid = threadIdx.x, wave = tid >> 6, lane = tid & 63;
    int wm = wave >> 1, wn = wave & 1, lrow = lane & 15, lk = lane >> 4;
#pragma unroll
    for (int mf = 0; mf < 4; ++mf) {
        int n = my * 128 + wm * 64 + mf * 16 + 4 * lk;
#pragma unroll
        for (int nf = 0; nf < 4; ++nf) {
            int m = nx * 128 + wn * 64 + nf * 16 + lrow;
#pragma unroll
            for (int rg = 0; rg < 4; ++rg)
                s[((size_t)b << 20) + (size_t)(n + rg) * NTOK_ + m] = acc[mf][nf][rg];
        }
    }
}

// ---------------- 8. softmax: fp32 row -> fp16 plane in place ----------------
__global__ __launch_bounds__(256) void softmax_kernel(float* __restrict__ s) {
    size_t row = blockIdx.x;
    float* p = s + (row << 10);
    int tid = threadIdx.x;
    f32x4 v = *(const f32x4*)&p[tid * 4];
    __shared__ float redm[4], reds[4];
    float m = fmaxf(fmaxf(v[0], v[1]), fmaxf(v[2], v[3]));
#pragma unroll
    for (int off = 32; off; off >>= 1) m = fmaxf(m, __shfl_down(m, off));
    int wid = tid >> 6, lane = tid & 63;
    if (lane == 0) redm[wid] = m;
    __syncthreads();
    m = fmaxf(fmaxf(redm[0], redm[1]), fmaxf(redm[2], redm[3]));
#pragma unroll
    for (int j = 0; j < 4; ++j) v[j] = __expf(v[j] - m);
    float sum = v[0] + v[1] + v[2] + v[3];
#pragma unroll
    for (int off = 32; off; off >>= 1) sum += __shfl_down(sum, off);
    if (lane == 0) reds[wid] = sum;
    __syncthreads();
    float inv = 1.f / (reds[0] + reds[1] + reds[2] + reds[3]);
    union { ushort u[4]; ushort4 w; } hh;
#pragma unroll
    for (int j = 0; j < 4; ++j) hh.u[j] = f2h(v[j] * inv);
    ushort* bp8 = (ushort*)p;  // row = 2048 ushorts; fp16 attn in [0,1024)
    *(ushort4*)&bp8[tid * 4] = hh.w;
}

// ---------------- 9. out = attn @ vp + bsum + x, NCHW ----------------
__global__ __launch_bounds__(256) void gemm_out(
    const float* __restrict__ s,
    const ushort* __restrict__ vpt16,
    const float* __restrict__ bsum, const float* __restrict__ x,
    float* __restrict__ out) {
    // swizzle (nwg=512)
    int D = blockIdx.x + (blockIdx.y << 2) + (blockIdx.z << 5);
    int L = ((D & 7) << 6) + (D >> 3);
    int ox = L & 3, ny = (L >> 2) & 7, b = L >> 5;

    const ushort* att = (const ushort*)s;
    const ushort* Ah = att + ((size_t)b * NTOK_ + ny * 128) * 2048;
    size_t bo = ((size_t)b * C_ + ox * 128) * NTOK_;
    f32x4 acc[4][4]; ACC_ZERO(acc);
    gemm_core_f16(Ah, 2048, vpt16 + bo, NTOK_, NTOK_, acc);

    int tid = threadIdx.x, wave = tid >> 6, lane = tid & 63;
    int wm = wave >> 1, wn = wave & 1, lrow = lane & 15, lk = lane >> 4;
#pragma unroll
    for (int mf = 0; mf < 4; ++mf) {
        int n0l = ny * 128 + wm * 64 + mf * 16 + 4 * lk;
#pragma unroll
        for (int nf = 0; nf < 4; ++nf) {
            int oc = ox * 128 + wn * 64 + nf * 16 + lrow;
            size_t base = ((size_t)b * C_ + oc) * NTOK_ + n0l;
            f32x4 xr = *(const f32x4*)&x[base];
            float bs = bsum[oc];
            f32x4 rv;
#pragma unroll
            for (int rg = 0; rg < 4; ++rg) rv[rg] = acc[mf][nf][rg] + bs + xr[rg];
            *(f32x4*)&out[base] = rv;
        }
    }
}

extern "C" void kernel_launch(void* const* d_in, const int* in_sizes, int n_in,
                              void* d_out, int out_size, void* d_ws, size_t ws_size,
                              hipStream_t stream) {
    const float* x  = (const float*)d_in[0];
    const float* gw = (const float*)d_in[1];
    const float* gb = (const float*)d_in[2];
    const float* wq = (const float*)d_in[3];
    const float* bq = (const float*)d_in[4];
    const float* wk = (const float*)d_in[5];
    const float* bk = (const float*)d_in[6];
    const float* wv = (const float*)d_in[7];
    const float* bv = (const float*)d_in[8];
    const float* wp = (const float*)d_in[9];
    const float* bp = (const float*)d_in[10];
    float* out = (float*)d_out;

    const size_t TOKC2 = (size_t)B_ * NTOK_ * C_ * 2;   // one fp16 plane (16 MB)
    const size_t W2 = (size_t)C_ * C_ * 2;               // 512 KB
    char* w = (char*)d_ws;
    auto carve = [&](size_t bytes) { char* p = w; w += (bytes + 255) & ~(size_t)255; return p; };

    float*  bsumv   = (float*)carve(C_ * 4);
    ushort* h16     = (ushort*)carve(TOKC2);
    ushort* wq16    = (ushort*)carve(W2);
    ushort* wk16    = (ushort*)carve(W2);
    ushort* we16    = (ushort*)carve(W2);
    ushort* q16     = (ushort*)carve(TOKC2);
    ushort* k16     = (ushort*)carve(TOKC2);
    ushort* vpt16   = (ushort*)carve(TOKC2);
    float*  scores  = (float*)carve((size_t)B_ * NTOK_ * NTOK_ * 4);  // 64 MB
    if ((size_t)(w - (char*)d_ws) > ws_size) return;

    gn_prep_kernel<<<B_ * 32, 256, 0, stream>>>(x, gw, gb, h16);
    prep_w_kernel<<<256, 256, 0, stream>>>(wq, wk, wq16, wk16);
    weff_kernel<<<dim3(8, 8), 256, 0, stream>>>(wp, wv, we16);
    bsum_kernel<<<128, 256, 0, stream>>>(wp, bv, bp, bsumv);
    gemm_qkv<<<dim3(12, 128), 256, 0, stream>>>(h16, wq16, wk16, we16, bq, bk,
                                                q16, k16, vpt16);
    gemm_scores<<<dim3(8, 8, B_), 256, 0, stream>>>(q16, k16, scores);
    softmax_kernel<<<B_ * NTOK_, 256, 0, stream>>>(scores);
    gemm_out<<<dim3(4, 8, B_), 256, 0, stream>>>(scores, vpt16, bsumv, x, out);
}

// Round 10
// 249.317 us; speedup vs baseline: 1.0805x; 1.0805x over previous
//
#include <hip/hip_runtime.h>
#include <hip/hip_bf16.h>

// AttnBlock: GroupNorm + single-head attention (N=1024 tokens, C=512) + residual.
// B=16. fp16 single-plane MFMA GEMMs (passing since R6, absmax 0.03125).
// R10 == R9 resubmitted (R9 never ran: GPU acquisition timeout).
// R9 changes vs R8 (269 us; R7 252.7 us):
//  - Revert R8's BK=32 experiment (it doubled the per-step drains; occupancy
//    never rose). Back to R7's BK=64, 2x32KB dbuf, proven LDS layout.
//  - THE fix (T4, m218): counted vmcnt instead of barrier drain. Per K-step:
//      stage(t+1); s_waitcnt vmcnt(8); s_barrier; ds_read+MFMA; s_barrier;
//    vmcnt(8) retires tile t's 8 loads but leaves t+1's 8 IN FLIGHT across
//    the barrier -> HBM latency overlaps compute. R6/R7/R8 all drained
//    vmcnt(0) at every step (pipeline-with-drain0 == no pipeline), which is
//    why qkv sat at ~43us across three structural variants.
//  - Race audit: per-wave vmcnt + barrier => all waves' tile-t data in LDS;
//    post-compute barrier precedes next overwrite of cur; all ds_reads are
//    consumed by MFMA (compiler lgkm waits, LDS ops retire in order) before
//    that barrier; uniform control flow; no vmem before the core in callers.
//  - Numerics bit-identical: absmax must remain exactly 0.03125.

#define B_ 16
#define C_ 512
#define NTOK_ 1024
#define CPG_ 16
#define EPS_ 1e-5f
#define QSCALE_ 0.04419417382415922f  // 512^-0.5

typedef __attribute__((ext_vector_type(8))) _Float16 f16x8;  // 4 VGPR
typedef __attribute__((ext_vector_type(4))) float f32x4;
typedef const void __attribute__((address_space(1)))* gas1_t;
typedef void __attribute__((address_space(3)))* las3_t;

__device__ __forceinline__ ushort f2h(float x) {
    union { _Float16 h; ushort u; } c; c.h = (_Float16)x; return c.u;
}

// =================== fp16 MFMA GEMM core (counted-vmcnt pipeline) ===================
// C[128 x 128] += A · B^T (rows of B = output cols), fp16 (as ushort*), K%64==0.
// acc[m][n]: wave (wm,wn); C row = wm*64+m*16+4*lk+reg, col = wn*64+n*16+lrow.
// LDS per buffer (32KB): A rows [0,16K), B [16K,32K); row=128B; 16B chunk c of
// a row at slot c^(row&7) -> conflict-free ds_read_b128 (R6: BANK_CONFLICT==0).
// Staged by global_load_lds w=16, pre-swizzled per-lane source
// (sel=(lane&7)^(lane>>3)); each wave stages its own 8KB quarter (8 x 1KB).
__device__ __forceinline__ void gemm_core_f16(
    const ushort* __restrict__ A, int lda,
    const ushort* __restrict__ B, int ldb,
    int K, f32x4 acc[4][4])
{
    __shared__ alignas(16) char ldsc[2][32768];
    const int tid  = threadIdx.x;
    const int wave = tid >> 6, lane = tid & 63;
    const int wm = wave >> 1, wn = wave & 1;
    const int lrow = lane & 15, lk = lane >> 4;

    // staging roles: waves 0,1 -> A rows [0,64)/[64,128); waves 2,3 -> B same.
    const int isB = wave >> 1;
    const ushort* P = isB ? B : A;
    const int ld = isB ? ldb : lda;
    const int sel = (lane & 7) ^ (lane >> 3);
    const int rowbase = ((wave & 1) << 6) + (lane >> 3);
    const ushort* src0 = P + (size_t)rowbase * ld + sel * 8;
    const int dstoff = (isB << 14) + ((wave & 1) << 13);

    const int nsteps = K >> 6;

#define STAGE(tt) do { \
    const ushort* st_ = src0 + (size_t)(tt) * 64; \
    char* dd_ = &ldsc[(tt) & 1][0] + dstoff; \
    _Pragma("unroll") \
    for (int j = 0; j < 8; ++j) { \
        __builtin_amdgcn_global_load_lds( \
            (gas1_t)(st_ + (size_t)(j << 3) * ld), \
            (las3_t)(dd_ + (j << 10)), 16, 0, 0); \
    } \
} while (0)

#define COMPUTE(tt) do { \
    const char* cur_ = &ldsc[(tt) & 1][0]; \
    f16x8 af[4][2], bf[4][2]; \
    _Pragma("unroll") \
    for (int m = 0; m < 4; ++m) { \
        int row = wm * 64 + m * 16 + lrow; \
        const char* base = cur_ + row * 128; \
        _Pragma("unroll") \
        for (int ks = 0; ks < 2; ++ks) { \
            int c = ks * 4 + lk; \
            af[m][ks] = *(const f16x8*)(base + ((c ^ (row & 7)) << 4)); \
        } \
    } \
    _Pragma("unroll") \
    for (int n = 0; n < 4; ++n) { \
        int row = wn * 64 + n * 16 + lrow; \
        const char* base = cur_ + 16384 + row * 128; \
        _Pragma("unroll") \
        for (int ks = 0; ks < 2; ++ks) { \
            int c = ks * 4 + lk; \
            bf[n][ks] = *(const f16x8*)(base + ((c ^ (row & 7)) << 4)); \
        } \
    } \
    _Pragma("unroll") \
    for (int m = 0; m < 4; ++m) \
    _Pragma("unroll") \
        for (int n = 0; n < 4; ++n) { \
            acc[m][n] = __builtin_amdgcn_mfma_f32_16x16x32_f16(af[m][0], bf[n][0], acc[m][n], 0, 0, 0); \
            acc[m][n] = __builtin_amdgcn_mfma_f32_16x16x32_f16(af[m][1], bf[n][1], acc[m][n], 0, 0, 0); \
        } \
} while (0)

    // prologue: stage tile 0 (8 loads in flight; NO drain here)
    STAGE(0);

    for (int t = 0; t < nsteps - 1; ++t) {
        STAGE(t + 1);  // now up to 16 outstanding: tile t's 8 + tile t+1's 8
        // retire tile t's loads only; t+1's stay in flight across the barrier
        asm volatile("s_waitcnt vmcnt(8)" ::: "memory");
        __builtin_amdgcn_sched_barrier(0);
        __builtin_amdgcn_s_barrier();
        __builtin_amdgcn_sched_barrier(0);
        COMPUTE(t);
        __builtin_amdgcn_sched_barrier(0);
        __builtin_amdgcn_s_barrier();  // all reads of buf t&1 done before t+2 overwrites
    }
    // last step: only tile (nsteps-1)'s 8 loads outstanding
    asm volatile("s_waitcnt vmcnt(0)" ::: "memory");
    __builtin_amdgcn_sched_barrier(0);
    __builtin_amdgcn_s_barrier();
    __builtin_amdgcn_sched_barrier(0);
    COMPUTE(nsteps - 1);

#undef STAGE
#undef COMPUTE
}

#define ACC_ZERO(acc) do { \
    _Pragma("unroll") for (int m_ = 0; m_ < 4; ++m_) \
    _Pragma("unroll") for (int n_ = 0; n_ < 4; ++n_) \
        acc[m_][n_] = (f32x4){0.f, 0.f, 0.f, 0.f}; \
} while (0)

// ---------------- 1. GroupNorm + affine + transpose -> h fp16 [b][n][c] ----------------
__global__ __launch_bounds__(256) void gn_prep_kernel(
    const float* __restrict__ x, const float* __restrict__ gw,
    const float* __restrict__ gb, ushort* __restrict__ h16) {
    __shared__ float sx[16][1028];   // +4 pad
    __shared__ float red[8];
    __shared__ float smu, srstd;
    __shared__ float s_sc[16], s_bi[16];
    int bg = blockIdx.x;
    int b = bg >> 5, g = bg & 31;
    const float* xp = x + ((size_t)(b * C_ + g * CPG_) << 10);
    int tid = threadIdx.x;
    float s = 0.f, ss = 0.f;
    for (int i = tid; i < 4096; i += 256) {   // 16 ch * 256 f32x4
        int c = i >> 8, n4 = (i & 255) << 2;
        f32x4 v = *(const f32x4*)&xp[((size_t)c << 10) + n4];
        *(f32x4*)&sx[c][n4] = v;
        s += v[0] + v[1] + v[2] + v[3];
        ss += v[0]*v[0] + v[1]*v[1] + v[2]*v[2] + v[3]*v[3];
    }
#pragma unroll
    for (int off = 32; off; off >>= 1) {
        s += __shfl_down(s, off);
        ss += __shfl_down(ss, off);
    }
    int wid = tid >> 6, lane = tid & 63;
    if (lane == 0) { red[wid] = s; red[wid + 4] = ss; }
    __syncthreads();
    if (tid == 0) {
        float S = red[0] + red[1] + red[2] + red[3];
        float SS = red[4] + red[5] + red[6] + red[7];
        float mu = S * (1.f / 16384.f);
        float var = SS * (1.f / 16384.f) - mu * mu;
        smu = mu;
        srstd = rsqrtf(var + EPS_);
    }
    __syncthreads();
    if (tid < CPG_) {
        int c = g * CPG_ + tid;
        float sc = srstd * gw[c];
        s_sc[tid] = sc;
        s_bi[tid] = gb[c] - smu * sc;
    }
    __syncthreads();
#pragma unroll
    for (int jn = 0; jn < 4; ++jn) {
        int n = (tid << 2) + jn;
        union { ushort u[16]; uint4 v[2]; } pk;
#pragma unroll
        for (int c = 0; c < 16; ++c)
            pk.u[c] = f2h(sx[c][n] * s_sc[c] + s_bi[c]);
        size_t ob = (((size_t)b << 10) + n) * C_ + g * CPG_;
        *(uint4*)&h16[ob] = pk.v[0];
        *(uint4*)&h16[ob + 8] = pk.v[1];
    }
}

// ---------------- 3. prep_w: wq, wk -> fp16 ----------------
__global__ __launch_bounds__(256) void prep_w_kernel(
    const float* __restrict__ wq, const float* __restrict__ wk,
    ushort* __restrict__ wq16, ushort* __restrict__ wk16) {
    int i = blockIdx.x * 256 + threadIdx.x;
    union { ushort u[4]; ushort4 v; } h;
    f32x4 a = ((const f32x4*)wq)[i];
#pragma unroll
    for (int j = 0; j < 4; ++j) h.u[j] = f2h(a[j]);
    ((ushort4*)wq16)[i] = h.v;
    f32x4 b = ((const f32x4*)wk)[i];
#pragma unroll
    for (int j = 0; j < 4; ++j) h.u[j] = f2h(b[j]);
    ((ushort4*)wk16)[i] = h.v;
}

// ---------------- 4. Weff = wp @ wv (fp32 VALU) -> fp16 ----------------
__global__ __launch_bounds__(256) void weff_kernel(
    const float* __restrict__ wp, const float* __restrict__ wv,
    ushort* __restrict__ we16) {
    __shared__ float As[16][68], Bs[16][68];
    int tid = threadIdx.x, ty = tid >> 4, tx = tid & 15;
    int c0 = blockIdx.x << 6, p0 = blockIdx.y << 6;
    int a_row = tid >> 2, a_kq = tid & 3;
    int b_m = tid >> 4, b_cq = tid & 15;
    float acc[4][4] = {};
    for (int k0 = 0; k0 < C_; k0 += 16) {
        f32x4 a4 = *(const f32x4*)&wp[(size_t)(p0 + a_row) * C_ + k0 + a_kq * 4];
        As[a_kq * 4 + 0][a_row] = a4[0]; As[a_kq * 4 + 1][a_row] = a4[1];
        As[a_kq * 4 + 2][a_row] = a4[2]; As[a_kq * 4 + 3][a_row] = a4[3];
        *(f32x4*)&Bs[b_m][b_cq * 4] =
            *(const f32x4*)&wv[(size_t)(k0 + b_m) * C_ + c0 + b_cq * 4];
        __syncthreads();
#pragma unroll
        for (int kk = 0; kk < 16; ++kk) {
            f32x4 av = *(const f32x4*)&As[kk][ty << 2];
            f32x4 bv = *(const f32x4*)&Bs[kk][tx << 2];
#pragma unroll
            for (int i = 0; i < 4; ++i)
#pragma unroll
                for (int j = 0; j < 4; ++j) acc[i][j] += av[i] * bv[j];
        }
        __syncthreads();
    }
#pragma unroll
    for (int i = 0; i < 4; ++i) {
        union { ushort u[4]; ushort4 v; } hh;
#pragma unroll
        for (int j = 0; j < 4; ++j) hh.u[j] = f2h(acc[i][j]);
        *(ushort4*)&we16[(size_t)(p0 + ty * 4 + i) * C_ + c0 + tx * 4] = hh.v;
    }
}

// ---------------- 5. bsum[p] = bp[p] + sum_o wp[p][o]*bv[o] ----------------
__global__ __launch_bounds__(256) void bsum_kernel(
    const float* __restrict__ wp, const float* __restrict__ bv,
    const float* __restrict__ bp, float* __restrict__ bsum) {
    int p = blockIdx.x * 4 + (threadIdx.x >> 6);   // grid 128 -> p in [0,512)
    int lane = threadIdx.x & 63;
    const float* row = wp + (size_t)p * C_;
    f32x4 w0 = *(const f32x4*)&row[lane * 8];
    f32x4 w1 = *(const f32x4*)&row[lane * 8 + 4];
    f32x4 b0 = *(const f32x4*)&bv[lane * 8];
    f32x4 b1 = *(const f32x4*)&bv[lane * 8 + 4];
    float s = w0[0]*b0[0] + w0[1]*b0[1] + w0[2]*b0[2] + w0[3]*b0[3]
            + w1[0]*b1[0] + w1[1]*b1[1] + w1[2]*b1[2] + w1[3]*b1[3];
#pragma unroll
    for (int off = 32; off; off >>= 1) s += __shfl_down(s, off);
    if (lane == 0) bsum[p] = bp[p] + s;
}

// ---------------- 6. qkv GEMM (q, k, vp^T from h) ----------------
__global__ __launch_bounds__(256) void gemm_qkv(
    const ushort* __restrict__ h16,
    const ushort* __restrict__ wq16, const ushort* __restrict__ wk16,
    const ushort* __restrict__ we16,
    const float* __restrict__ bq, const float* __restrict__ bk,
    ushort* __restrict__ q16, ushort* __restrict__ k16,
    ushort* __restrict__ vpt16) {
    // XCD-chunked bijective swizzle (nwg=1536, %8==0)
    int D = blockIdx.x + 12 * blockIdx.y;
    int L = ((D & 7) * 192) + (D >> 3);
    int lx = L % 12, mt = L / 12;
    int wsel = lx >> 2, ct = lx & 3;

    const ushort* Bw = wsel == 0 ? wq16 : (wsel == 1 ? wk16 : we16);
    const float* bias = wsel == 0 ? bq : bk;

    f32x4 acc[4][4]; ACC_ZERO(acc);
    gemm_core_f16(h16 + (size_t)mt * 128 * C_, C_,
                  Bw + (size_t)ct * 128 * C_, C_, C_, acc);

    int tid = threadIdx.x, wave = tid >> 6, lane = tid & 63;
    int wm = wave >> 1, wn = wave & 1, lrow = lane & 15, lk = lane >> 4;

    if (wsel < 2) {
        ushort* oh = wsel ? k16 : q16;
        float scale = wsel ? 1.f : QSCALE_;
#pragma unroll
        for (int mf = 0; mf < 4; ++mf) {
            int gm = mt * 128 + wm * 64 + mf * 16 + 4 * lk;
#pragma unroll
            for (int nf = 0; nf < 4; ++nf) {
                int gc = ct * 128 + wn * 64 + nf * 16 + lrow;
                float bi = bias[gc];
#pragma unroll
                for (int rg = 0; rg < 4; ++rg)
                    oh[(size_t)(gm + rg) * C_ + gc] = f2h((acc[mf][nf][rg] + bi) * scale);
            }
        }
    } else {
        // vp^T [b][p][n]: 4 consecutive token-rows per reg-quad -> 8B stores
#pragma unroll
        for (int mf = 0; mf < 4; ++mf) {
            int gm0 = mt * 128 + wm * 64 + mf * 16 + 4 * lk;
            int b = gm0 >> 10, nl = gm0 & 1023;
#pragma unroll
            for (int nf = 0; nf < 4; ++nf) {
                int p = ct * 128 + wn * 64 + nf * 16 + lrow;
                union { ushort u[4]; ushort4 v; } hv;
#pragma unroll
                for (int rg = 0; rg < 4; ++rg) hv.u[rg] = f2h(acc[mf][nf][rg]);
                *(ushort4*)&vpt16[((size_t)b * C_ + p) * NTOK_ + nl] = hv.v;
            }
        }
    }
}

// ---------------- 7. scores = q @ k^T (per batch), fp32 out ----------------
__global__ __launch_bounds__(256) void gemm_scores(
    const ushort* __restrict__ q16, const ushort* __restrict__ k16,
    float* __restrict__ s) {
    // swizzle (nwg=1024)
    int D = blockIdx.x + (blockIdx.y << 3) + (blockIdx.z << 6);
    int L = ((D & 7) << 7) + (D >> 3);
    int nx = L & 7, my = (L >> 3) & 7, b = L >> 6;

    size_t ao = ((size_t)b * NTOK_ + my * 128) * C_;
    size_t bo = ((size_t)b * NTOK_ + nx * 128) * C_;
    f32x4 acc[4][4]; ACC_ZERO(acc);
    gemm_core_f16(q16 + ao, C_, k16 + bo, C_, C_, acc);

    int tid = threadIdx.x, wave = tid >> 6, lane = tid & 63;
    int wm = wave >> 1, wn = wave & 1, lrow = lane & 15, lk = lane >> 4;
#pragma unroll
    for (int mf = 0; mf < 4; ++mf) {
        int n = my * 128 + wm * 64 + mf * 16 + 4 * lk;
#pragma unroll
        for (int nf = 0; nf < 4; ++nf) {
            int m = nx * 128 + wn * 64 + nf * 16 + lrow;
#pragma unroll
            for (int rg = 0; rg < 4; ++rg)
                s[((size_t)b << 20) + (size_t)(n + rg) * NTOK_ + m] = acc[mf][nf][rg];
        }
    }
}

// ---------------- 8. softmax: fp32 row -> fp16 plane in place ----------------
__global__ __launch_bounds__(256) void softmax_kernel(float* __restrict__ s) {
    size_t row = blockIdx.x;
    float* p = s + (row << 10);
    int tid = threadIdx.x;
    f32x4 v = *(const f32x4*)&p[tid * 4];
    __shared__ float redm[4], reds[4];
    float m = fmaxf(fmaxf(v[0], v[1]), fmaxf(v[2], v[3]));
#pragma unroll
    for (int off = 32; off; off >>= 1) m = fmaxf(m, __shfl_down(m, off));
    int wid = tid >> 6, lane = tid & 63;
    if (lane == 0) redm[wid] = m;
    __syncthreads();
    m = fmaxf(fmaxf(redm[0], redm[1]), fmaxf(redm[2], redm[3]));
#pragma unroll
    for (int j = 0; j < 4; ++j) v[j] = __expf(v[j] - m);
    float sum = v[0] + v[1] + v[2] + v[3];
#pragma unroll
    for (int off = 32; off; off >>= 1) sum += __shfl_down(sum, off);
    if (lane == 0) reds[wid] = sum;
    __syncthreads();
    float inv = 1.f / (reds[0] + reds[1] + reds[2] + reds[3]);
    union { ushort u[4]; ushort4 w; } hh;
#pragma unroll
    for (int j = 0; j < 4; ++j) hh.u[j] = f2h(v[j] * inv);
    ushort* bp8 = (ushort*)p;  // row = 2048 ushorts; fp16 attn in [0,1024)
    *(ushort4*)&bp8[tid * 4] = hh.w;
}

// ---------------- 9. out = attn @ vp + bsum + x, NCHW ----------------
__global__ __launch_bounds__(256) void gemm_out(
    const float* __restrict__ s,
    const ushort* __restrict__ vpt16,
    const float* __restrict__ bsum, const float* __restrict__ x,
    float* __restrict__ out) {
    // swizzle (nwg=512)
    int D = blockIdx.x + (blockIdx.y << 2) + (blockIdx.z << 5);
    int L = ((D & 7) << 6) + (D >> 3);
    int ox = L & 3, ny = (L >> 2) & 7, b = L >> 5;

    const ushort* att = (const ushort*)s;
    const ushort* Ah = att + ((size_t)b * NTOK_ + ny * 128) * 2048;
    size_t bo = ((size_t)b * C_ + ox * 128) * NTOK_;
    f32x4 acc[4][4]; ACC_ZERO(acc);
    gemm_core_f16(Ah, 2048, vpt16 + bo, NTOK_, NTOK_, acc);

    int tid = threadIdx.x, wave = tid >> 6, lane = tid & 63;
    int wm = wave >> 1, wn = wave & 1, lrow = lane & 15, lk = lane >> 4;
#pragma unroll
    for (int mf = 0; mf < 4; ++mf) {
        int n0l = ny * 128 + wm * 64 + mf * 16 + 4 * lk;
#pragma unroll
        for (int nf = 0; nf < 4; ++nf) {
            int oc = ox * 128 + wn * 64 + nf * 16 + lrow;
            size_t base = ((size_t)b * C_ + oc) * NTOK_ + n0l;
            f32x4 xr = *(const f32x4*)&x[base];
            float bs = bsum[oc];
            f32x4 rv;
#pragma unroll
            for (int rg = 0; rg < 4; ++rg) rv[rg] = acc[mf][nf][rg] + bs + xr[rg];
            *(f32x4*)&out[base] = rv;
        }
    }
}

extern "C" void kernel_launch(void* const* d_in, const int* in_sizes, int n_in,
                              void* d_out, int out_size, void* d_ws, size_t ws_size,
                              hipStream_t stream) {
    const float* x  = (const float*)d_in[0];
    const float* gw = (const float*)d_in[1];
    const float* gb = (const float*)d_in[2];
    const float* wq = (const float*)d_in[3];
    const float* bq = (const float*)d_in[4];
    const float* wk = (const float*)d_in[5];
    const float* bk = (const float*)d_in[6];
    const float* wv = (const float*)d_in[7];
    const float* bv = (const float*)d_in[8];
    const float* wp = (const float*)d_in[9];
    const float* bp = (const float*)d_in[10];
    float* out = (float*)d_out;

    const size_t TOKC2 = (size_t)B_ * NTOK_ * C_ * 2;   // one fp16 plane (16 MB)
    const size_t W2 = (size_t)C_ * C_ * 2;               // 512 KB
    char* w = (char*)d_ws;
    auto carve = [&](size_t bytes) { char* p = w; w += (bytes + 255) & ~(size_t)255; return p; };

    float*  bsumv   = (float*)carve(C_ * 4);
    ushort* h16     = (ushort*)carve(TOKC2);
    ushort* wq16    = (ushort*)carve(W2);
    ushort* wk16    = (ushort*)carve(W2);
    ushort* we16    = (ushort*)carve(W2);
    ushort* q16     = (ushort*)carve(TOKC2);
    ushort* k16     = (ushort*)carve(TOKC2);
    ushort* vpt16   = (ushort*)carve(TOKC2);
    float*  scores  = (float*)carve((size_t)B_ * NTOK_ * NTOK_ * 4);  // 64 MB
    if ((size_t)(w - (char*)d_ws) > ws_size) return;

    gn_prep_kernel<<<B_ * 32, 256, 0, stream>>>(x, gw, gb, h16);
    prep_w_kernel<<<256, 256, 0, stream>>>(wq, wk, wq16, wk16);
    weff_kernel<<<dim3(8, 8), 256, 0, stream>>>(wp, wv, we16);
    bsum_kernel<<<128, 256, 0, stream>>>(wp, bv, bp, bsumv);
    gemm_qkv<<<dim3(12, 128), 256, 0, stream>>>(h16, wq16, wk16, we16, bq, bk,
                                                q16, k16, vpt16);
    gemm_scores<<<dim3(8, 8, B_), 256, 0, stream>>>(q16, k16, scores);
    softmax_kernel<<<B_ * NTOK_, 256, 0, stream>>>(scores);
    gemm_out<<<dim3(4, 8, B_), 256, 0, stream>>>(scores, vpt16, bsumv, x, out);
}